// Round 6
// baseline (433.628 us; speedup 1.0000x reference)
//
#include <hip/hip_runtime.h>
#include <math.h>

// out[b] = prod_g w2*(wn + w0*x^2)/(wn + x^2), wn = w1^2, G=127 genes/row.
//
// History: R2 LDS tile 4 waves/CU -> 0.85 TB/s. R3 strided float4, rolled loop
// (VGPR=12) -> 2.0 TB/s + 400 MB overfetch. R4 global_load_lds slabs -> 2.4 TB/s.
// R5 pipelined DMA -> identical to R4 => the DMA path itself is throttled
// (~2.4 TB/s/device), not wave latency. Fill kernel proves 6.7 TB/s with plain
// VGPR traffic.
//
// R6: plain VGPR loads, deep MLP, no staging.
//  - thread owns 4 rows = 2032 B (16B-aligned; single rows are not), 127
//    independent global_load_dwordx4 via immediate offsets off one base.
//  - explicit 8-deep prefetch ring, fully unrolled loop: all row-emit/renorm
//    points compile-time -> no rolled loop (R3's killer), and same-cache-line
//    touches (k..k+3) issue within ~200 cyc -> MSHR merge, no overfetch.
//  - weights via LDS broadcast ds_read_b64 from 4 REPLICATED tables (distinct
//    immediate offset per unrolled read) so GVN can't CSE 254 values into regs.
//  - global scale S = prod(w0*w2) ~ 1e-82: kept as (mant, exp), per-wave
//    shuffle reduction. frexp renorm every 8 genes; ldexpf underflows to
//    0/denormal exactly like the fp32 reference (R1 lesson: naive products
//    hit 0/0 = NaN).

constexpr int G = 127;
constexpr int RPT = 4;               // rows per thread; 4*127 floats = 2032 B
constexpr int BLK = 256;
constexpr int PF = 8;                // float4 loads in flight per lane
constexpr int NK = RPT * G / 4;      // 127 float4 loads per thread

__global__ __launch_bounds__(BLK)
void hill_kernel(const float* __restrict__ x, const float* __restrict__ w,
                 float* __restrict__ out)
{
    __shared__ float2 wt[RPT][G];    // 4 identical copies (anti-CSE: unique offsets)
    __shared__ float  sw[G];

    const int tid = threadIdx.x;
    if (tid < G) {
        float w0 = w[3 * tid], w1 = w[3 * tid + 1], w2 = w[3 * tid + 2];
        float wn = w1 * w1;
        float2 ab = make_float2(wn / w0, wn);   // h = (w0*w2) * (xn + wn/w0)/(xn + wn)
#pragma unroll
        for (int r = 0; r < RPT; ++r) wt[r][tid] = ab;
        sw[tid] = w0 * w2;
    }
    __syncthreads();

    // Global scale S = prod_g (w0*w2), identical for all rows; mant+exp since
    // S ~ 1e-82 underflows fp32. Redundant per-wave shuffle reduction.
    const int lane = tid & 63;
    float Sm = sw[lane] * ((lane + 64 < G) ? sw[lane + 64] : 1.0f);
    int Se; Sm = frexpf(Sm, &Se);
#pragma unroll
    for (int d = 1; d < 64; d <<= 1) {
        Sm *= __shfl_xor(Sm, d);
        Se += __shfl_xor(Se, d);
        int e; Sm = frexpf(Sm, &e); Se += e;
    }

    const size_t t_global = (size_t)blockIdx.x * BLK + tid;
    const float4* __restrict__ xp =
        reinterpret_cast<const float4*>(x + t_global * (size_t)(RPT * G));

    // Prime the prefetch ring: 8 x 1KB/wave in flight, steady-state.
    float4 pf[PF];
#pragma unroll
    for (int k = 0; k < PF; ++k) pf[k] = xp[k];

    float res[RPT];
    float pn = 1.0f, pd = 1.0f;
    int ex = 0;

#pragma unroll
    for (int k = 0; k < NK; ++k) {           // fully unrolled, 127 iterations
        float4 v = pf[k % PF];
        if (k + PF < NK) pf[k % PF] = xp[k + PF];
#pragma unroll
        for (int j = 0; j < 4; ++j) {
            int e = 4 * k + j;               // compile-time after unroll
            int r = e / G;
            int g = e % G;
            float xe = (j == 0) ? v.x : (j == 1) ? v.y : (j == 2) ? v.z : v.w;
            float2 ab = wt[r][g];            // ds_read_b64, unique imm offset
            float xn = xe * xe;
            pn *= (xn + ab.x);
            pd *= (xn + ab.y);
            if ((g & 7) == 7 || g == G - 1) {  // renorm: chunk of <=8 genes,
                int e1, e2;                    // worst case 1e-16, no underflow
                pn = frexpf(pn, &e1);
                pd = frexpf(pd, &e2);
                ex += e1 - e2;
            }
            if (g == G - 1) {                // row complete (compile-time point)
                res[r] = ldexpf(Sm * pn / pd, Se + ex);
                pn = 1.0f; pd = 1.0f; ex = 0;
            }
        }
    }

    // 4 contiguous outputs per thread -> one coalesced 16B store.
    reinterpret_cast<float4*>(out)[t_global] =
        make_float4(res[0], res[1], res[2], res[3]);
}

extern "C" void kernel_launch(void* const* d_in, const int* in_sizes, int n_in,
                              void* d_out, int out_size, void* d_ws, size_t ws_size,
                              hipStream_t stream) {
    const float* x = (const float*)d_in[0];
    const float* w = (const float*)d_in[1];
    float* out = (float*)d_out;

    const int B = in_sizes[0] / G;           // 524288
    const int blocks = B / (RPT * BLK);      // 512

    hipLaunchKernelGGL(hill_kernel, dim3(blocks), dim3(BLK), 0, stream, x, w, out);
}